// Round 5
// baseline (35.836 us; speedup 1.0000x reference)
//
#include <hip/hip_runtime.h>

// MaxUnpool2D: in [16,64,64,128] f32, mask [16,64,64,128] i32 (flat NHWC index
// with Ho=128, Wo=128, guaranteed inside the 2x2 window of each input elem),
// out [16,128,128,128] f32.
//
// R5: output-centric gather (R4 structure) + persistent streaming blocks.
// Grid = 2048 blocks (16 b x 64 h x 2 halves), 256 threads, each block loops
// over 16 wc chunks -> sequential 16KB in + 16KB mask read stream and two
// sequential 32KB output row segments per block. 8 blocks/CU x 4 waves = full
// occupancy; 16 independent iterations give ILP for load/store pipelining.
// Both output rows of each 2x2 window live in the same block => no HBM read
// amplification. No NT (R3: nt bypassing L2 defeats write-combining, -10%).

typedef float f32x4 __attribute__((ext_vector_type(4)));
typedef int   i32x4 __attribute__((ext_vector_type(4)));

__global__ __launch_bounds__(256) void MaxUnpool2D_59047210385945_kernel(
    const f32x4* __restrict__ in, const i32x4* __restrict__ mask,
    f32x4* __restrict__ out) {
    // bid = [b:4][h:6][half:1]
    int bid  = blockIdx.x;
    int half = bid & 1;
    int h    = (bid >> 1) & 63;
    int b    = bid >> 7;

    int tid = threadIdx.x;
    int c4  = tid & 31;         // float4 channel group (C/4 = 32)
    int wl  = (tid >> 5) & 3;   // wo within 4-wide chunk
    int dh  = tid >> 7;         // output row parity

    int ho = (h << 1) + dh;

    // Base indices (float4 units).
    // input:  ((b*64 + h)*64 + w)*32 + c4,  w = ((half*16 + j)*4 + wl) >> 1
    // output: ((b*128 + ho)*128 + wo)*32 + c4
    int in_row_base  = ((((b << 6) + h) << 6)) << 5;         // (b,h,0,0)
    int out_row_base = ((((b << 7) + ho) << 7)) << 5;        // (b,ho,0,0)

    #pragma unroll 4
    for (int j = 0; j < 16; ++j) {
        int wc = (half << 4) + j;
        int wo = (wc << 2) + wl;
        int w  = wo >> 1;
        int dw = wo & 1;

        int iin = in_row_base + (w << 5) + c4;
        f32x4 v = in[iin];
        i32x4 m = mask[iin];

        f32x4 o;
        #pragma unroll
        for (int k = 0; k < 4; ++k) {
            int sel_dh = (m[k] >> 14) & 1;  // dh of argmax
            int sel_dw = (m[k] >> 7) & 1;   // dw of argmax
            o[k] = (sel_dh == dh && sel_dw == dw) ? v[k] : 0.0f;
        }

        out[out_row_base + (wo << 5) + c4] = o;
    }
}

extern "C" void kernel_launch(void* const* d_in, const int* in_sizes, int n_in,
                              void* d_out, int out_size, void* d_ws, size_t ws_size,
                              hipStream_t stream) {
    const f32x4* in   = (const f32x4*)d_in[0];
    const i32x4* mask = (const i32x4*)d_in[1];
    f32x4*       out  = (f32x4*)d_out;

    // 16*64*2 = 2048 blocks x 256 threads, 16 output float4 per thread.
    MaxUnpool2D_59047210385945_kernel<<<2048, 256, 0, stream>>>(in, mask, out);
}